// Round 1
// baseline (322.401 us; speedup 1.0000x reference)
//
#include <hip/hip_runtime.h>
#include <stdint.h>

// B=4, M=4096, HID=1024, H=16, HD=64, SEG=128, nseg=32, DIL=2, SCALE=0.125
// out = ((perm-gathered x) @ Wqkv^T -> segment attention with parity mask) @ Wout^T

typedef __attribute__((ext_vector_type(8))) short short8;
typedef __attribute__((ext_vector_type(4))) short short4v;
typedef __attribute__((ext_vector_type(4))) float f32x4;

#define DEV __device__ __forceinline__

DEV short f2bf(float f) {
  union { float f; uint32_t u; } x; x.f = f;
  uint32_t r = x.u + 0x7fffu + ((x.u >> 16) & 1u);
  return (short)(r >> 16);
}

DEV void gload_lds16(const void* g, void* l) {
  __builtin_amdgcn_global_load_lds(
      (const __attribute__((address_space(1))) uint32_t*)g,
      (__attribute__((address_space(3))) uint32_t*)l, 16, 0, 0);
}

// ---------------- converts ----------------
__global__ __launch_bounds__(256) void k_gather_cast(
    const float* __restrict__ x, const int* __restrict__ perm, short* __restrict__ xp) {
  const int row = blockIdx.x;             // b*4096 + pos (permuted order)
  const int b = row >> 12, pos = row & 4095;
  const int src = (b << 12) + perm[pos];
  const f32x4 v = ((const f32x4*)(x + (size_t)src * 1024))[threadIdx.x];
  short4v o = { f2bf(v[0]), f2bf(v[1]), f2bf(v[2]), f2bf(v[3]) };
  ((short4v*)(xp + (size_t)row * 1024))[threadIdx.x] = o;
}

__global__ __launch_bounds__(256) void k_cast(
    const float* __restrict__ src, short* __restrict__ dst) {
  const int i = blockIdx.x * 256 + threadIdx.x;
  const f32x4 v = ((const f32x4*)src)[i];
  short4v o = { f2bf(v[0]), f2bf(v[1]), f2bf(v[2]), f2bf(v[3]) };
  ((short4v*)dst)[i] = o;
}

// ---------------- GEMM: C = A(MxK) * W(NxK)^T, 128x128 tile, BK=64 ----------------
// EPI==0: scatter-write C as bf16 into qkv ws laid out (3,B,H,M,HD)
// EPI==1: write C fp32 row-major (N cols)
template <int EPI>
__global__ __launch_bounds__(256, 3) void k_gemm(
    const short* __restrict__ A, const short* __restrict__ W,
    void* __restrict__ Cout, const int K, const int N) {
  __shared__ __attribute__((aligned(16))) short As[128 * 64];
  __shared__ __attribute__((aligned(16))) short Bs[128 * 64];
  const int tid = threadIdx.x;
  const int bi = blockIdx.y, bj = blockIdx.x;
  const int lane = tid & 63, w = tid >> 6;
  const int wr = w >> 1, wc = w & 1;
  const int lrow = lane & 15, lg = lane >> 4;

  f32x4 acc[4][4] = {};
  const size_t arow0 = (size_t)bi * 128;
  const size_t brow0 = (size_t)bj * 128;

  for (int k0 = 0; k0 < K; k0 += 64) {
    __syncthreads();
    // stage 128x64 bf16 tiles; linear LDS dest + pre-swizzled global source
    // (logical chunk g lands at phys chunk g ^ (row&7))
#pragma unroll
    for (int i = 0; i < 4; ++i) {
      int c = i * 256 + tid;         // chunk 0..1023 (16B each)
      int row = c >> 3, ch = c & 7;
      int g = ch ^ (row & 7);
      gload_lds16(A + (arow0 + row) * K + k0 + g * 8, &As[c * 8]);
      gload_lds16(W + (brow0 + row) * K + k0 + g * 8, &Bs[c * 8]);
    }
    __syncthreads();
#pragma unroll
    for (int kk = 0; kk < 2; ++kk) {
      short8 af[4], bfr[4];
#pragma unroll
      for (int mi = 0; mi < 4; ++mi) {
        int r = wr * 64 + mi * 16 + lrow;
        int pc = (kk * 4 + lg) ^ (r & 7);
        af[mi] = *(const short8*)&As[r * 64 + pc * 8];
      }
#pragma unroll
      for (int ni = 0; ni < 4; ++ni) {
        int r = wc * 64 + ni * 16 + lrow;
        int pc = (kk * 4 + lg) ^ (r & 7);
        bfr[ni] = *(const short8*)&Bs[r * 64 + pc * 8];
      }
#pragma unroll
      for (int mi = 0; mi < 4; ++mi)
#pragma unroll
        for (int ni = 0; ni < 4; ++ni)
          acc[mi][ni] = __builtin_amdgcn_mfma_f32_16x16x32_bf16(
              af[mi], bfr[ni], acc[mi][ni], 0, 0, 0);
    }
  }

  const int gr_base = bi * 128 + wr * 64;
  const int gc_base = bj * 128 + wc * 64;
  if (EPI == 0) {
    short* Q = (short*)Cout;
#pragma unroll
    for (int mi = 0; mi < 4; ++mi) {
#pragma unroll
      for (int reg = 0; reg < 4; ++reg) {
        int gr = gr_base + mi * 16 + 4 * lg + reg;   // b*4096+pos
        int b = gr >> 12, pos = gr & 4095;
#pragma unroll
        for (int ni = 0; ni < 4; ++ni) {
          int gc = gc_base + ni * 16 + lrow;         // 0..3071
          int sel = gc >> 10, h = (gc >> 6) & 15, d = gc & 63;
          size_t idx = ((((size_t)sel * 4 + b) * 16 + h) * 4096 + pos) * 64 + d;
          Q[idx] = f2bf(acc[mi][ni][reg]);
        }
      }
    }
  } else {
    float* C = (float*)Cout;
#pragma unroll
    for (int mi = 0; mi < 4; ++mi)
#pragma unroll
      for (int reg = 0; reg < 4; ++reg) {
        int gr = gr_base + mi * 16 + 4 * lg + reg;
#pragma unroll
        for (int ni = 0; ni < 4; ++ni) {
          int gc = gc_base + ni * 16 + lrow;
          C[(size_t)gr * N + gc] = acc[mi][ni][reg];
        }
      }
  }
}

// ---------------- segment attention ----------------
// one block per (b,h,seg): S = Q K^T * 0.125, mask (s odd & t odd), softmax, O = P V
__global__ __launch_bounds__(256, 2) void k_attn(
    const short* __restrict__ qkv, short* __restrict__ aout) {
  __shared__ __attribute__((aligned(16))) short Qs[128 * 64];
  __shared__ __attribute__((aligned(16))) short Ks[128 * 64];
  __shared__ __attribute__((aligned(16))) short Vt[64 * 128];   // transposed [d][t]
  __shared__ __attribute__((aligned(16))) short Ps[128 * 128];
  const int bid = blockIdx.x;
  const int seg = bid & 31, h = (bid >> 5) & 15, b = bid >> 9;
  const size_t plane = (size_t)4096 * 64;
  const short* qp = qkv + ((size_t)(0 * 4 + b) * 16 + h) * plane + seg * 128 * 64;
  const short* kp = qkv + ((size_t)(1 * 4 + b) * 16 + h) * plane + seg * 128 * 64;
  const short* vp = qkv + ((size_t)(2 * 4 + b) * 16 + h) * plane + seg * 128 * 64;
  const int tid = threadIdx.x, lane = tid & 63, w = tid >> 6;
  const int lrow = lane & 15, lg = lane >> 4;

#pragma unroll
  for (int i = 0; i < 4; ++i) {
    int c = i * 256 + tid;
    int row = c >> 3, ch = c & 7, g = ch ^ (row & 7);
    gload_lds16(qp + row * 64 + g * 8, &Qs[c * 8]);
    gload_lds16(kp + row * 64 + g * 8, &Ks[c * 8]);
  }
  // V: coalesced 16B global loads, transposed+swizzled LDS writes
#pragma unroll
  for (int i = 0; i < 4; ++i) {
    int c = i * 256 + tid;
    int t = c >> 3, d0 = (c & 7) * 8;
    short8 v = *(const short8*)(vp + t * 64 + d0);
#pragma unroll
    for (int j = 0; j < 8; ++j) {
      int d = d0 + j;
      Vt[d * 128 + (t ^ ((d & 7) * 8))] = v[j];
    }
  }
  __syncthreads();

  // S = Q K^T : wave w owns rows w*32..w*32+31, all 128 cols
  f32x4 s[2][8] = {};
#pragma unroll
  for (int kk = 0; kk < 2; ++kk) {
    short8 qa[2];
#pragma unroll
    for (int mi = 0; mi < 2; ++mi) {
      int r = w * 32 + mi * 16 + lrow;
      int pc = (kk * 4 + lg) ^ (r & 7);
      qa[mi] = *(const short8*)&Qs[r * 64 + pc * 8];
    }
#pragma unroll
    for (int ni = 0; ni < 8; ++ni) {
      int r = ni * 16 + lrow;
      int pc = (kk * 4 + lg) ^ (r & 7);
      short8 kb = *(const short8*)&Ks[r * 64 + pc * 8];
#pragma unroll
      for (int mi = 0; mi < 2; ++mi)
        s[mi][ni] = __builtin_amdgcn_mfma_f32_16x16x32_bf16(qa[mi], kb, s[mi][ni], 0, 0, 0);
    }
  }

  // masked softmax per row; C-layout: row=4*lg+reg (parity=reg&1), col=lane&15 (parity=lane&1)
  float inv[2][4];
  const int oddcol = lane & 1;
#pragma unroll
  for (int mi = 0; mi < 2; ++mi) {
#pragma unroll
    for (int reg = 0; reg < 4; ++reg) {
      float pm = -3.0e38f;
#pragma unroll
      for (int ni = 0; ni < 8; ++ni) {
        float v = s[mi][ni][reg] * 0.125f;
        if ((reg & 1) && oddcol) v = -1.0e30f;
        s[mi][ni][reg] = v;
        pm = fmaxf(pm, v);
      }
#pragma unroll
      for (int off = 1; off < 16; off <<= 1) pm = fmaxf(pm, __shfl_xor(pm, off));
      float sum = 0.f;
#pragma unroll
      for (int ni = 0; ni < 8; ++ni) {
        float p = __expf(s[mi][ni][reg] - pm);
        s[mi][ni][reg] = p;
        sum += p;
      }
#pragma unroll
      for (int off = 1; off < 16; off <<= 1) sum += __shfl_xor(sum, off);
      inv[mi][reg] = 1.0f / sum;
    }
  }

  // store P (unnormalized) to LDS, swizzled; wave reads back only its own rows
#pragma unroll
  for (int mi = 0; mi < 2; ++mi)
#pragma unroll
    for (int ni = 0; ni < 8; ++ni)
#pragma unroll
      for (int reg = 0; reg < 4; ++reg) {
        int r = w * 32 + mi * 16 + 4 * lg + reg;
        int col = ni * 16 + lrow;
        Ps[r * 128 + (col ^ ((r & 7) * 8))] = f2bf(s[mi][ni][reg]);
      }

  // O = P V
  f32x4 o[2][4] = {};
#pragma unroll
  for (int kt = 0; kt < 4; ++kt) {
    short8 pa[2];
#pragma unroll
    for (int mi = 0; mi < 2; ++mi) {
      int r = w * 32 + mi * 16 + lrow;
      int pc = (kt * 4 + lg) ^ (r & 7);
      pa[mi] = *(const short8*)&Ps[r * 128 + pc * 8];
    }
#pragma unroll
    for (int dn = 0; dn < 4; ++dn) {
      int d = dn * 16 + lrow;
      int pc = (kt * 4 + lg) ^ (d & 7);
      short8 vb = *(const short8*)&Vt[d * 128 + pc * 8];
#pragma unroll
      for (int mi = 0; mi < 2; ++mi)
        o[mi][dn] = __builtin_amdgcn_mfma_f32_16x16x32_bf16(pa[mi], vb, o[mi][dn], 0, 0, 0);
    }
  }

  // write attn-out bf16 at rows (b*4096+pos), cols h*64+d  (still permuted order)
#pragma unroll
  for (int mi = 0; mi < 2; ++mi)
#pragma unroll
    for (int dn = 0; dn < 4; ++dn)
#pragma unroll
      for (int reg = 0; reg < 4; ++reg) {
        int r = w * 32 + mi * 16 + 4 * lg + reg;
        int pos = seg * 128 + r;
        int d = dn * 16 + lrow;
        aout[((size_t)(b * 4096 + pos)) * 1024 + h * 64 + d] =
            f2bf(o[mi][dn][reg] * inv[mi][reg]);
      }
}

// ---------------- launch ----------------
extern "C" void kernel_launch(void* const* d_in, const int* in_sizes, int n_in,
                              void* d_out, int out_size, void* d_ws, size_t ws_size,
                              hipStream_t stream) {
  const float* x     = (const float*)d_in[0];
  const float* w_qkv = (const float*)d_in[1];
  const float* w_out = (const float*)d_in[2];
  const int*   perm  = (const int*)d_in[3];

  char* ws = (char*)d_ws;
  short* xp   = (short*)(ws);                               // 16384*1024 bf16 (33.5MB)
  short* wq   = (short*)(ws + 33554432);                    // 3072*1024  (6.3MB)
  short* wo   = (short*)(ws + 33554432 + 6291456);          // 1024*1024  (2.1MB)
  short* qkvb = (short*)(ws + 41943040);                    // 3*4*16*4096*64 (100.7MB)
  short* aout = xp;  // xp is dead after GEMM1 -> reuse for attention output

  k_gather_cast<<<16384, 256, 0, stream>>>(x, perm, xp);
  k_cast<<<3072, 256, 0, stream>>>(w_qkv, wq);              // 3072*1024/4 elems per thread*4
  k_cast<<<1024, 256, 0, stream>>>(w_out, wo);
  k_gemm<0><<<dim3(24, 128), 256, 0, stream>>>(xp, wq, qkvb, 1024, 3072);
  k_attn<<<2048, 256, 0, stream>>>(qkvb, aout);
  k_gemm<1><<<dim3(8, 128), 256, 0, stream>>>(aout, wo, d_out, 1024, 1024);
}

// Round 2
// 308.856 us; speedup vs baseline: 1.0439x; 1.0439x over previous
//
#include <hip/hip_runtime.h>
#include <stdint.h>

// B=4, M=4096, HID=1024, H=16, HD=64, SEG=128, nseg=32, DIL=2, SCALE=0.125
// out = ((perm-gathered x) @ Wqkv^T -> segment attention with parity mask) @ Wout^T

typedef __attribute__((ext_vector_type(8))) short short8;
typedef __attribute__((ext_vector_type(4))) short short4v;
typedef __attribute__((ext_vector_type(4))) float f32x4;

#define DEV __device__ __forceinline__

DEV short f2bf(float f) {
  union { float f; uint32_t u; } x; x.f = f;
  uint32_t r = x.u + 0x7fffu + ((x.u >> 16) & 1u);
  return (short)(r >> 16);
}

DEV void gload_lds16(const void* g, void* l) {
  __builtin_amdgcn_global_load_lds(
      (const __attribute__((address_space(1))) uint32_t*)g,
      (__attribute__((address_space(3))) uint32_t*)l, 16, 0, 0);
}

#define BAR() __builtin_amdgcn_s_barrier()
#define LGKM0() do { asm volatile("s_waitcnt lgkmcnt(0)" ::: "memory"); \
                     __builtin_amdgcn_sched_barrier(0); } while (0)
#define VMC(n) asm volatile("s_waitcnt vmcnt(" #n ")" ::: "memory")

// ---------------- converts ----------------
__global__ __launch_bounds__(256) void k_gather_cast(
    const float* __restrict__ x, const int* __restrict__ perm, short* __restrict__ xp) {
  const int row = blockIdx.x;             // b*4096 + pos (permuted order)
  const int b = row >> 12, pos = row & 4095;
  const int src = (b << 12) + perm[pos];
  const f32x4 v = ((const f32x4*)(x + (size_t)src * 1024))[threadIdx.x];
  short4v o = { f2bf(v[0]), f2bf(v[1]), f2bf(v[2]), f2bf(v[3]) };
  ((short4v*)(xp + (size_t)row * 1024))[threadIdx.x] = o;
}

__global__ __launch_bounds__(256) void k_cast(
    const float* __restrict__ src, short* __restrict__ dst) {
  const int i = blockIdx.x * 256 + threadIdx.x;
  const f32x4 v = ((const f32x4*)src)[i];
  short4v o = { f2bf(v[0]), f2bf(v[1]), f2bf(v[2]), f2bf(v[3]) };
  ((short4v*)dst)[i] = o;
}

// ---------------- 256x256 8-phase GEMM: C = A(MxK) * W(NxK)^T, K=1024 ----------------
// 8 waves 2(M)x4(N); per-wave C = rows {wr*64..+63}u{128+wr*64..+63} x cols {wc*32..+31}u{128+wc*32..+31}
// LDS: 2 dbuf x (A 256x64 + B 256x64) bf16 = 128 KiB, T2-swizzled via pre-swizzled global src.
// Phase (mh,nh) reads only A-half mh / B-half nh. Counted vmcnt(4) once per K-tile (T4), setprio (T5).
// EPI==0: scatter bf16 into qkv ws laid out (3,B,H,M,HD).  EPI==1: fp32 row-major N=1024.
template <int EPI, int NBJ>
__global__ __launch_bounds__(512, 2) void k_gemm8(
    const short* __restrict__ A, const short* __restrict__ W, void* __restrict__ Cout) {
  __shared__ __attribute__((aligned(16))) short lds[65536];   // 128 KiB
  const int tid = threadIdx.x;
  const int lane = tid & 63, w = tid >> 6;
  const int wr = w >> 2, wc = w & 3;
  const int lrow = lane & 15, lg = lane >> 4;

  // XCD-aware swizzle (grid = NBJ*64, divisible by 8)
  const int nwg = NBJ * 64;
  const int cpx = nwg >> 3;
  const int bid = blockIdx.x;
  const int sw = (bid & 7) * cpx + (bid >> 3);
  const int bi = sw / NBJ, bj = sw % NBJ;

  const short* Abase = A + (size_t)bi * 256 * 1024;
  const short* Bbase = W + (size_t)bj * 256 * 1024;

  // staging thread-constants: 2 x 16B chunks per thread per 128x64 half-tile
  const int c0 = tid, c1 = tid + 512;
  const int sOff0 = (c0 >> 3) * 1024 + (((c0 & 7) ^ ((c0 >> 3) & 7)) * 8);
  const int sOff1 = (c1 >> 3) * 1024 + (((c1 & 7) ^ ((c1 >> 3) & 7)) * 8);
  // ds_read swizzled chunk (row&7 == lrow&7 since 16-row frag strides)
  const int pc0 = lg ^ (lrow & 7), pc1 = (4 + lg) ^ (lrow & 7);

  f32x4 acc[2][4][2][2] = {};   // [mh][mi][nh][ni]
  short8 af[4][2], bfrag[2][2][2];

#define ISSUE(base, half, tile, isB) do {                                   \
    const short* _s = (base) + (half) * (128 * 1024) + (tile) * 64;         \
    short* _d = lds + (((tile) & 1) * 32768) + (isB) * 16384 + (half) * 8192; \
    gload_lds16(_s + sOff0, _d + c0 * 8);                                   \
    gload_lds16(_s + sOff1, _d + c1 * 8);                                   \
  } while (0)

#define LDA(mh) do {                                                        \
    const short* _b = ldsbuf + (mh) * 8192;                                 \
    _Pragma("unroll") for (int mi = 0; mi < 4; ++mi) {                      \
      const short* _r = _b + (wr * 64 + mi * 16 + lrow) * 64;               \
      af[mi][0] = *(const short8*)(_r + pc0 * 8);                           \
      af[mi][1] = *(const short8*)(_r + pc1 * 8); } } while (0)

#define LDB(nh) do {                                                        \
    const short* _b = ldsbuf + 16384 + (nh) * 8192;                         \
    _Pragma("unroll") for (int ni = 0; ni < 2; ++ni) {                      \
      const short* _r = _b + (wc * 32 + ni * 16 + lrow) * 64;               \
      bfrag[nh][ni][0] = *(const short8*)(_r + pc0 * 8);                    \
      bfrag[nh][ni][1] = *(const short8*)(_r + pc1 * 8); } } while (0)

#define MM(mh, nh) do {                                                     \
    _Pragma("unroll") for (int mi = 0; mi < 4; ++mi)                        \
    _Pragma("unroll") for (int ni = 0; ni < 2; ++ni) {                      \
      acc[mh][mi][nh][ni] = __builtin_amdgcn_mfma_f32_16x16x32_bf16(        \
          af[mi][0], bfrag[nh][ni][0], acc[mh][mi][nh][ni], 0, 0, 0);       \
      acc[mh][mi][nh][ni] = __builtin_amdgcn_mfma_f32_16x16x32_bf16(        \
          af[mi][1], bfrag[nh][ni][1], acc[mh][mi][nh][ni], 0, 0, 0); } } while (0)

  // prologue: tile0 all 4 halves + tile1 {Ah0,Bh0}; wait for tile0, keep 4 loads in flight
  ISSUE(Abase, 0, 0, 0); ISSUE(Bbase, 0, 0, 1);
  ISSUE(Abase, 1, 0, 0); ISSUE(Bbase, 1, 0, 1);
  ISSUE(Abase, 0, 1, 0); ISSUE(Bbase, 0, 1, 1);
  VMC(4);
  BAR();

#pragma unroll 2
  for (int t = 0; t < 16; ++t) {
    const short* ldsbuf = lds + ((t & 1) * 32768);
    // ph1: quadrant (mh0,nh0); prefetch Ah1(t+1)
    LDA(0); LDB(0);
    if (t + 1 < 16) ISSUE(Abase, 1, t + 1, 0);
    BAR(); LGKM0();
    __builtin_amdgcn_s_setprio(1); MM(0, 0); __builtin_amdgcn_s_setprio(0);
    BAR();
    // ph2: (mh0,nh1); prefetch Bh1(t+1)
    LDB(1);
    if (t + 1 < 16) ISSUE(Bbase, 1, t + 1, 1);
    BAR(); LGKM0();
    __builtin_amdgcn_s_setprio(1); MM(0, 1); __builtin_amdgcn_s_setprio(0);
    BAR();
    // ph3: (mh1,nh0); prefetch Ah0(t+2) into current buf (A0 dead since ph1)
    LDA(1);
    if (t + 2 < 16) ISSUE(Abase, 0, t + 2, 0);
    BAR(); LGKM0();
    __builtin_amdgcn_s_setprio(1); MM(1, 0); __builtin_amdgcn_s_setprio(0);
    BAR();
    // ph4: (mh1,nh1); prefetch Bh0(t+2); counted vmcnt certifies tile t+1 resident
    if (t + 2 < 16) ISSUE(Bbase, 0, t + 2, 1);
    BAR(); LGKM0();
    __builtin_amdgcn_s_setprio(1); MM(1, 1); __builtin_amdgcn_s_setprio(0);
    if (t + 2 < 16) { VMC(4); } else { VMC(0); }
    BAR();
  }
#undef ISSUE
#undef LDA
#undef LDB
#undef MM

  if (EPI == 0) {
    short* Q = (short*)Cout;
#pragma unroll
    for (int mh = 0; mh < 2; ++mh)
#pragma unroll
    for (int mi = 0; mi < 4; ++mi)
#pragma unroll
    for (int reg = 0; reg < 4; ++reg) {
      const int gr = bi * 256 + mh * 128 + wr * 64 + mi * 16 + 4 * lg + reg;
      const int b = gr >> 12, pos = gr & 4095;
#pragma unroll
      for (int nh = 0; nh < 2; ++nh)
#pragma unroll
      for (int ni = 0; ni < 2; ++ni) {
        const int gc = bj * 256 + nh * 128 + wc * 32 + ni * 16 + lrow;
        const int sel = gc >> 10, h = (gc >> 6) & 15, d = gc & 63;
        Q[((((size_t)sel * 4 + b) * 16 + h) * 4096 + pos) * 64 + d] =
            f2bf(acc[mh][mi][nh][ni][reg]);
      }
    }
  } else {
    float* C = (float*)Cout;
#pragma unroll
    for (int mh = 0; mh < 2; ++mh)
#pragma unroll
    for (int mi = 0; mi < 4; ++mi)
#pragma unroll
    for (int reg = 0; reg < 4; ++reg) {
      const int gr = bi * 256 + mh * 128 + wr * 64 + mi * 16 + 4 * lg + reg;
#pragma unroll
      for (int nh = 0; nh < 2; ++nh)
#pragma unroll
      for (int ni = 0; ni < 2; ++ni) {
        const int gc = bj * 256 + nh * 128 + wc * 32 + ni * 16 + lrow;
        C[(size_t)gr * 1024 + gc] = acc[mh][mi][nh][ni][reg];
      }
    }
  }
}

// ---------------- segment attention ----------------
// one block per (b,h,seg): S = Q K^T * 0.125, mask (s odd & t odd), softmax, O = P V
// LDS 48KB: Qs[0,8K) Ks[8K,16K) Vt[16K,24K) shorts; Ps aliases [0,16K) (Q/K dead after QK^T)
__global__ __launch_bounds__(256, 3) void k_attn(
    const short* __restrict__ qkv, short* __restrict__ aout) {
  __shared__ __attribute__((aligned(16))) short smem[24576];
  short* Qs = smem;
  short* Ks = smem + 8192;
  short* Vt = smem + 16384;   // transposed [d][t]
  short* Ps = smem;           // alias over Qs+Ks
  const int bid = blockIdx.x;
  const int seg = bid & 31, h = (bid >> 5) & 15, b = bid >> 9;
  const size_t plane = (size_t)4096 * 64;
  const short* qp = qkv + ((size_t)(0 * 4 + b) * 16 + h) * plane + seg * 128 * 64;
  const short* kp = qkv + ((size_t)(1 * 4 + b) * 16 + h) * plane + seg * 128 * 64;
  const short* vp = qkv + ((size_t)(2 * 4 + b) * 16 + h) * plane + seg * 128 * 64;
  const int tid = threadIdx.x, lane = tid & 63, w = tid >> 6;
  const int lrow = lane & 15, lg = lane >> 4;

#pragma unroll
  for (int i = 0; i < 4; ++i) {
    int c = i * 256 + tid;
    int row = c >> 3, ch = c & 7, g = ch ^ (row & 7);
    gload_lds16(qp + row * 64 + g * 8, &Qs[c * 8]);
    gload_lds16(kp + row * 64 + g * 8, &Ks[c * 8]);
  }
  // V: coalesced 16B global loads, transposed+swizzled LDS writes
#pragma unroll
  for (int i = 0; i < 4; ++i) {
    int c = i * 256 + tid;
    int t = c >> 3, d0 = (c & 7) * 8;
    short8 v = *(const short8*)(vp + t * 64 + d0);
#pragma unroll
    for (int j = 0; j < 8; ++j) {
      int d = d0 + j;
      Vt[d * 128 + (t ^ ((d & 7) * 8))] = v[j];
    }
  }
  __syncthreads();

  // S = Q K^T : wave w owns rows w*32..w*32+31, all 128 cols
  f32x4 s[2][8] = {};
  __builtin_amdgcn_s_setprio(1);
#pragma unroll
  for (int kk = 0; kk < 2; ++kk) {
    short8 qa[2];
#pragma unroll
    for (int mi = 0; mi < 2; ++mi) {
      int r = w * 32 + mi * 16 + lrow;
      int pc = (kk * 4 + lg) ^ (r & 7);
      qa[mi] = *(const short8*)&Qs[r * 64 + pc * 8];
    }
#pragma unroll
    for (int ni = 0; ni < 8; ++ni) {
      int r = ni * 16 + lrow;
      int pc = (kk * 4 + lg) ^ (r & 7);
      short8 kb = *(const short8*)&Ks[r * 64 + pc * 8];
#pragma unroll
      for (int mi = 0; mi < 2; ++mi)
        s[mi][ni] = __builtin_amdgcn_mfma_f32_16x16x32_bf16(qa[mi], kb, s[mi][ni], 0, 0, 0);
    }
  }
  __builtin_amdgcn_s_setprio(0);

  // masked softmax per row; C-layout: row=4*lg+reg (parity=reg&1), col=lane&15 (parity=lane&1)
  float inv[2][4];
  const int oddcol = lane & 1;
#pragma unroll
  for (int mi = 0; mi < 2; ++mi) {
#pragma unroll
    for (int reg = 0; reg < 4; ++reg) {
      float pm = -3.0e38f;
#pragma unroll
      for (int ni = 0; ni < 8; ++ni) {
        float v = s[mi][ni][reg] * 0.125f;
        if ((reg & 1) && oddcol) v = -1.0e30f;
        s[mi][ni][reg] = v;
        pm = fmaxf(pm, v);
      }
#pragma unroll
      for (int off = 1; off < 16; off <<= 1) pm = fmaxf(pm, __shfl_xor(pm, off));
      float sum = 0.f;
#pragma unroll
      for (int ni = 0; ni < 8; ++ni) {
        float p = __expf(s[mi][ni][reg] - pm);
        s[mi][ni][reg] = p;
        sum += p;
      }
#pragma unroll
      for (int off = 1; off < 16; off <<= 1) sum += __shfl_xor(sum, off);
      inv[mi][reg] = 1.0f / sum;
    }
  }

  __syncthreads();   // all QK^T LDS reads done before Ps overwrites Qs/Ks

  // store P (unnormalized) to LDS, swizzled; wave reads back only its own rows
#pragma unroll
  for (int mi = 0; mi < 2; ++mi)
#pragma unroll
    for (int ni = 0; ni < 8; ++ni)
#pragma unroll
      for (int reg = 0; reg < 4; ++reg) {
        int r = w * 32 + mi * 16 + 4 * lg + reg;
        int col = ni * 16 + lrow;
        Ps[r * 128 + (col ^ ((r & 7) * 8))] = f2bf(s[mi][ni][reg]);
      }

  // O = P V
  f32x4 o[2][4] = {};
  __builtin_amdgcn_s_setprio(1);
#pragma unroll
  for (int kt = 0; kt < 4; ++kt) {
    short8 pa[2];
#pragma unroll
    for (int mi = 0; mi < 2; ++mi) {
      int r = w * 32 + mi * 16 + lrow;
      int pc = (kt * 4 + lg) ^ (r & 7);
      pa[mi] = *(const short8*)&Ps[r * 128 + pc * 8];
    }
#pragma unroll
    for (int dn = 0; dn < 4; ++dn) {
      int d = dn * 16 + lrow;
      int pc = (kt * 4 + lg) ^ (d & 7);
      short8 vb = *(const short8*)&Vt[d * 128 + pc * 8];
#pragma unroll
      for (int mi = 0; mi < 2; ++mi)
        o[mi][dn] = __builtin_amdgcn_mfma_f32_16x16x32_bf16(pa[mi], vb, o[mi][dn], 0, 0, 0);
    }
  }
  __builtin_amdgcn_s_setprio(0);

  // write attn-out bf16 at rows (b*4096+pos), cols h*64+d  (still permuted order)
#pragma unroll
  for (int mi = 0; mi < 2; ++mi)
#pragma unroll
    for (int dn = 0; dn < 4; ++dn)
#pragma unroll
      for (int reg = 0; reg < 4; ++reg) {
        int r = w * 32 + mi * 16 + 4 * lg + reg;
        int pos = seg * 128 + r;
        int d = dn * 16 + lrow;
        aout[((size_t)(b * 4096 + pos)) * 1024 + h * 64 + d] =
            f2bf(o[mi][dn][reg] * inv[mi][reg]);
      }
}

// ---------------- launch ----------------
extern "C" void kernel_launch(void* const* d_in, const int* in_sizes, int n_in,
                              void* d_out, int out_size, void* d_ws, size_t ws_size,
                              hipStream_t stream) {
  const float* x     = (const float*)d_in[0];
  const float* w_qkv = (const float*)d_in[1];
  const float* w_out = (const float*)d_in[2];
  const int*   perm  = (const int*)d_in[3];

  char* ws = (char*)d_ws;
  short* xp   = (short*)(ws);                               // 16384*1024 bf16 (33.5MB)
  short* wq   = (short*)(ws + 33554432);                    // 3072*1024  (6.3MB)
  short* wo   = (short*)(ws + 33554432 + 6291456);          // 1024*1024  (2.1MB)
  short* qkvb = (short*)(ws + 41943040);                    // 3*4*16*4096*64 (100.7MB)
  short* aout = xp;  // xp is dead after GEMM1 -> reuse for attention output

  k_gather_cast<<<16384, 256, 0, stream>>>(x, perm, xp);
  k_cast<<<3072, 256, 0, stream>>>(w_qkv, wq);
  k_cast<<<1024, 256, 0, stream>>>(w_out, wo);
  k_gemm8<0, 12><<<768, 512, 0, stream>>>(xp, wq, qkvb);
  k_attn<<<2048, 256, 0, stream>>>(qkvb, aout);
  k_gemm8<1, 4><<<256, 512, 0, stream>>>(aout, wo, d_out);
}